// Round 11
// baseline (101.694 us; speedup 1.0000x reference)
//
#include <hip/hip_runtime.h>
#include <math.h>

#define H_COLS 256
#define G_SEGS 8192
#define SEGS_PER_BLOCK 4

typedef float f32x4 __attribute__((ext_vector_type(4)));

// Wave-cooperative 64-ary lower_bound: smallest i with ids[i] >= t.
// 4 dependent rounds for N=524288; top-tree probes are L2-shared across waves.
__device__ __forceinline__ int lower_bound_wave(const int* __restrict__ ids,
                                                int n, int t, int lane) {
    int lo = 0, hi = n;
    while (hi - lo > 1) {
        int span = hi - lo;
        int m = lo + ((span * lane) >> 6);
        unsigned long long mask = __ballot(ids[m] < t);
        if (mask == 0) return lo;
        int j = 63 - __clzll(mask);
        int nlo = lo + ((span * j) >> 6) + 1;
        int nhi = (j < 63) ? (lo + ((span * (j + 1)) >> 6)) : hi;
        lo = nlo;
        hi = nhi;
    }
    if (hi == lo) return lo;
    return (ids[lo] >= t) ? lo : hi;
}

// One wave per segment (8192 waves = 32/CU), lane l owns columns [4l,4l+3]
// via 16B nontemporal loads (R10's +12% win: no L1/L2 allocation churn on the
// zero-reuse 512 MiB stream). A/B vs R10: ONLY change is unroll 4 -> 8 —
// with nt loads at full HBM latency the optimal per-wave MLP may be deeper.
__global__ __launch_bounds__(256) void seg_lse(const float* __restrict__ x,
                                               const int* __restrict__ ids,
                                               float* __restrict__ out, int n) {
    const int wave = threadIdx.x >> 6;
    const int lane = threadIdx.x & 63;
    const int g = blockIdx.x * SEGS_PER_BLOCK + wave;

    const int s0 = lower_bound_wave(ids, n, g, lane);
    const int s1 = lower_bound_wave(ids, n, g + 1, lane);

    const f32x4* __restrict__ xp = reinterpret_cast<const f32x4*>(x) + lane;

    // Peel row s0: defines the shift; its own contribution is exp(0)=1.
    f32x4 mv = __builtin_nontemporal_load(&xp[(size_t)s0 * (H_COLS / 4)]);
    const float m0 = mv.x, m1 = mv.y, m2 = mv.z, m3 = mv.w;
    const float K = 1.44269504088896f;  // log2(e)
    const float b0 = m0 * K, b1 = m1 * K, b2 = m2 * K, b3 = m3 * K;
    float a0 = 1.f, a1 = 1.f, a2 = 1.f, a3 = 1.f;

#pragma unroll 8
    for (int r = s0 + 1; r < s1; ++r) {
        f32x4 v = __builtin_nontemporal_load(&xp[(size_t)r * (H_COLS / 4)]);
        a0 += exp2f(__builtin_fmaf(v.x, K, -b0));
        a1 += exp2f(__builtin_fmaf(v.y, K, -b1));
        a2 += exp2f(__builtin_fmaf(v.z, K, -b2));
        a3 += exp2f(__builtin_fmaf(v.w, K, -b3));
    }

    f32x4 o;
    o.x = m0 + logf(a0);
    o.y = m1 + logf(a1);
    o.z = m2 + logf(a2);
    o.w = m3 + logf(a3);
    __builtin_nontemporal_store(o, &reinterpret_cast<f32x4*>(out)[(size_t)g * (H_COLS / 4) + lane]);
}

extern "C" void kernel_launch(void* const* d_in, const int* in_sizes, int n_in,
                              void* d_out, int out_size, void* d_ws, size_t ws_size,
                              hipStream_t stream) {
    const float* seq_rep = (const float*)d_in[0];
    const int* pair_ids = (const int*)d_in[1];
    float* out = (float*)d_out;
    int n = in_sizes[1];  // N rows

    seg_lse<<<G_SEGS / SEGS_PER_BLOCK, 256, 0, stream>>>(seq_rep, pair_ids, out, n);
}

// Round 12
// 97.929 us; speedup vs baseline: 1.0385x; 1.0385x over previous
//
#include <hip/hip_runtime.h>
#include <math.h>

#define H_COLS 256
#define G_SEGS 8192
#define SEGS_PER_BLOCK 4

typedef float f32x4 __attribute__((ext_vector_type(4)));

// Wave-cooperative 64-ary lower_bound: smallest i with ids[i] >= t.
// 4 dependent rounds for N=524288; top-tree probes are L2-shared across waves.
__device__ __forceinline__ int lower_bound_wave(const int* __restrict__ ids,
                                                int n, int t, int lane) {
    int lo = 0, hi = n;
    while (hi - lo > 1) {
        int span = hi - lo;
        int m = lo + ((span * lane) >> 6);
        unsigned long long mask = __ballot(ids[m] < t);
        if (mask == 0) return lo;
        int j = 63 - __clzll(mask);
        int nlo = lo + ((span * j) >> 6) + 1;
        int nhi = (j < 63) ? (lo + ((span * (j + 1)) >> 6)) : hi;
        lo = nlo;
        hi = nhi;
    }
    if (hi == lo) return lo;
    return (ids[lo] >= t) ? lo : hi;
}

// Best configuration (R10): one wave per segment (8192 waves = 32/CU, the
// measured concurrency knee), lane l owns columns [4l,4l+3] via 16B
// nontemporal loads (+12%: no L1/L2 allocation churn on the zero-reuse
// 512 MiB stream), shift fixed from the segment's first row (LSE
// shift-invariance), body = v_fma + v_exp with only the add loop-carried,
// unroll 4 = measured-optimal MLP (unroll 8 regressed both cached and nt).
__global__ __launch_bounds__(256) void seg_lse(const float* __restrict__ x,
                                               const int* __restrict__ ids,
                                               float* __restrict__ out, int n) {
    const int wave = threadIdx.x >> 6;
    const int lane = threadIdx.x & 63;
    const int g = blockIdx.x * SEGS_PER_BLOCK + wave;

    const int s0 = lower_bound_wave(ids, n, g, lane);
    const int s1 = lower_bound_wave(ids, n, g + 1, lane);

    const f32x4* __restrict__ xp = reinterpret_cast<const f32x4*>(x) + lane;

    // Peel row s0: defines the shift; its own contribution is exp(0)=1.
    f32x4 mv = __builtin_nontemporal_load(&xp[(size_t)s0 * (H_COLS / 4)]);
    const float m0 = mv.x, m1 = mv.y, m2 = mv.z, m3 = mv.w;
    const float K = 1.44269504088896f;  // log2(e)
    const float b0 = m0 * K, b1 = m1 * K, b2 = m2 * K, b3 = m3 * K;
    float a0 = 1.f, a1 = 1.f, a2 = 1.f, a3 = 1.f;

#pragma unroll 4
    for (int r = s0 + 1; r < s1; ++r) {
        f32x4 v = __builtin_nontemporal_load(&xp[(size_t)r * (H_COLS / 4)]);
        a0 += exp2f(__builtin_fmaf(v.x, K, -b0));
        a1 += exp2f(__builtin_fmaf(v.y, K, -b1));
        a2 += exp2f(__builtin_fmaf(v.z, K, -b2));
        a3 += exp2f(__builtin_fmaf(v.w, K, -b3));
    }

    f32x4 o;
    o.x = m0 + logf(a0);
    o.y = m1 + logf(a1);
    o.z = m2 + logf(a2);
    o.w = m3 + logf(a3);
    __builtin_nontemporal_store(o, &reinterpret_cast<f32x4*>(out)[(size_t)g * (H_COLS / 4) + lane]);
}

extern "C" void kernel_launch(void* const* d_in, const int* in_sizes, int n_in,
                              void* d_out, int out_size, void* d_ws, size_t ws_size,
                              hipStream_t stream) {
    const float* seq_rep = (const float*)d_in[0];
    const int* pair_ids = (const int*)d_in[1];
    float* out = (float*)d_out;
    int n = in_sizes[1];  // N rows

    seg_lse<<<G_SEGS / SEGS_PER_BLOCK, 256, 0, stream>>>(seq_rep, pair_ids, out, n);
}